// Round 18
// baseline (363.537 us; speedup 1.0000x reference)
//
#include <hip/hip_runtime.h>
#include <hip/hip_fp16.h>

#define BATCH 32
#define TLEN  4096
#define CH    128      // C == F == 128
#define KW    3
#define DIL   8

#define BM    128                // output rows per block
#define HR    (BM + 2 * DIL)     // 144  h rows needed
#define WROWS (BM + 4 * DIL)     // 160  x rows needed
#define LDSC  132                // 264B stride ≡ 2 (mod 32 dwords): ~2-way free.

typedef _Float16 f16x8 __attribute__((ext_vector_type(8)));
typedef float    f32x4 __attribute__((ext_vector_type(4)));

// ---------------------------------------------------------------------------
// Prep: Wt[j][f][c] = (f16) W[c][j][f]
// ---------------------------------------------------------------------------
__global__ void prep_weights_kernel(const float* __restrict__ W1,
                                    const float* __restrict__ W2,
                                    _Float16* __restrict__ Wt1,
                                    _Float16* __restrict__ Wt2) {
    const int total = KW * CH * CH;
    int idx = blockIdx.x * 256 + threadIdx.x;
    if (idx >= 2 * total) return;
    const float* W  = (idx < total) ? W1 : W2;
    _Float16*    Wt = (idx < total) ? Wt1 : Wt2;
    int r = idx % total;
    int j = r / (CH * CH);
    int f = (r / CH) % CH;
    int c = r % CH;
    Wt[j * CH * CH + f * CH + c] = (_Float16)W[c * (KW * CH) + j * CH + f];
}

// ---------------------------------------------------------------------------
// ABLATION build of the r14 kernel (best: 66.6us).
//   VAR=0: full kernel (the real one; launched LAST, overwrites all of out).
//   VAR=1: stage writes ZEROS (no global x loads / cvt)  -> stage cost.
//   VAR=2: both GEMM loops skipped (ds_read+MFMA gone); w1/w2 kept live via
//          asm keepers, hs kept via volatile read (rule 17)  -> GEMM cost.
//   VAR=3: epilogue computed but not stored (asm keeper)   -> store cost.
// REPS repeats the whole body (same tile) to scale variant durations into
// the profiler-visible range. All variants are deterministic.
// ---------------------------------------------------------------------------
template<int VAR, int REPS>
__global__ __launch_bounds__(256)
void fused_deconv_kernel(const float* __restrict__ x,
                         const _Float16* __restrict__ Wt1,
                         const float* __restrict__ bias1,
                         const _Float16* __restrict__ Wt2,
                         const float* __restrict__ bias2,
                         float* __restrict__ out)
{
    __shared__ __align__(16) _Float16 xs[WROWS][LDSC];   // 42240 B
    __shared__ __align__(16) _Float16 hs[HR][LDSC];      // 38016 B

    const int tid  = threadIdx.x;
    const int lane = tid & 63;
    const int wid  = tid >> 6;         // 0..3
    const int l15  = lane & 15;
    const int kg   = lane >> 4;        // 0..3
    const int nc   = wid << 5;         // wave column base: 0,32,64,96

    const int bt0 = blockIdx.x;
    const int bt  = (bt0 & 7) * 128 + (bt0 >> 3);   // XCD-bijective swizzle
    const int b   = bt >> 5;
    const int t0  = (bt & 31) << 7;

    const float bv1_0 = 128.0f * bias1[nc + l15];
    const float bv1_1 = 128.0f * bias1[nc + 16 + l15];
    const float bv2_0 = 128.0f * bias2[nc + l15];
    const float bv2_1 = 128.0f * bias2[nc + 16 + l15];

#pragma unroll 1
    for (int rep = 0; rep < REPS; ++rep) {

        // ---- w1 prefetch (24 x 16B); in flight over stage
        f16x8 w1[12][2];
#pragma unroll
        for (int ks = 0; ks < 12; ++ks) {
            const int j  = ks >> 2;
            const int c0 = (ks & 3) << 5;
            const _Float16* wb = Wt1 + (size_t)j * (CH * CH) + c0 + kg * 8;
            w1[ks][0] = *(const f16x8*)(wb + (nc + l15) * CH);
            w1[ks][1] = *(const f16x8*)(wb + (nc + 16 + l15) * CH);
        }
        if constexpr (VAR == 2) {
#pragma unroll
            for (int ks = 0; ks < 12; ++ks)
                asm volatile("" :: "v"(w1[ks][0]), "v"(w1[ks][1]));
        }

        // ---- stage x window (VAR=1: zeros only)
#pragma unroll
        for (int p = 0; p < 10; ++p) {
            const int i   = tid + 256 * p;
            const int row = i >> 4;
            const int c8  = (i & 15) << 3;
            f16x8 o;
            if constexpr (VAR == 1) {
                o = (f16x8){};
            } else {
                const int t = t0 + row;
                if (t < TLEN) {
                    const float* xp = x + ((size_t)b * TLEN + t) * CH + c8;
                    f32x4 v0 = *(const f32x4*)(xp + 0);
                    f32x4 v1 = *(const f32x4*)(xp + 4);
                    o[0] = (_Float16)v0[0]; o[1] = (_Float16)v0[1];
                    o[2] = (_Float16)v0[2]; o[3] = (_Float16)v0[3];
                    o[4] = (_Float16)v1[0]; o[5] = (_Float16)v1[1];
                    o[6] = (_Float16)v1[2]; o[7] = (_Float16)v1[3];
                } else {
                    o = (f16x8){};
                }
            }
            *(f16x8*)&xs[row][c8] = o;
        }

        __syncthreads();   // barrier 1: xs published

        // ---- GEMM1 (skipped in VAR=2)
        f32x4 acc1[9][2];
#pragma unroll
        for (int m = 0; m < 9; ++m) {
            acc1[m][0] = (f32x4){0.f, 0.f, 0.f, 0.f};
            acc1[m][1] = (f32x4){0.f, 0.f, 0.f, 0.f};
        }
        if constexpr (VAR != 2) {
#pragma unroll
            for (int ks = 0; ks < 12; ++ks) {
                const int j     = ks >> 2;
                const int c0    = (ks & 3) << 5;
                const int shift = (2 - j) * DIL;
#pragma unroll
                for (int m = 0; m < 9; ++m) {
                    f16x8 af = *(const f16x8*)&xs[m * 16 + shift + l15][c0 + kg * 8];
                    acc1[m][0] = __builtin_amdgcn_mfma_f32_16x16x32_f16(af, w1[ks][0], acc1[m][0], 0, 0, 0);
                    acc1[m][1] = __builtin_amdgcn_mfma_f32_16x16x32_f16(af, w1[ks][1], acc1[m][1], 0, 0, 0);
                }
            }
        }

        // ---- w2 prefetch; in flight over h-store
        f16x8 w2[12][2];
#pragma unroll
        for (int ks = 0; ks < 12; ++ks) {
            const int j  = ks >> 2;
            const int c0 = (ks & 3) << 5;
            const _Float16* wb = Wt2 + (size_t)j * (CH * CH) + c0 + kg * 8;
            w2[ks][0] = *(const f16x8*)(wb + (nc + l15) * CH);
            w2[ks][1] = *(const f16x8*)(wb + (nc + 16 + l15) * CH);
        }
        if constexpr (VAR == 2) {
#pragma unroll
            for (int ks = 0; ks < 12; ++ks)
                asm volatile("" :: "v"(w2[ks][0]), "v"(w2[ks][1]));
        }

        // ---- h-store
#pragma unroll
        for (int m = 0; m < 9; ++m) {
#pragma unroll
            for (int nn = 0; nn < 2; ++nn) {
                const float bv = nn ? bv1_1 : bv1_0;
                const int f = nc + nn * 16 + l15;
#pragma unroll
                for (int i = 0; i < 4; ++i) {
                    const int r = m * 16 + kg * 4 + i;
                    const int u = t0 + r;
                    const int nv = 1 + (u < TLEN - DIL) + (u < TLEN - 2 * DIL);
                    float v = acc1[m][nn][i] + (float)nv * bv;
                    v = fmaxf(v, 0.0f);
                    hs[r][f] = (u < TLEN) ? (_Float16)v : (_Float16)0.0f;
                }
            }
        }
        __syncthreads();   // barrier 2: hs published

        if constexpr (VAR == 2) {
            // keep hs array observed so its stores aren't DCE'd (rule 17)
            volatile const _Float16* hp = &hs[0][0];
            float kk = (float)hp[(tid * 131) % (HR * LDSC)];
            asm volatile("" :: "v"(kk));
        }

        // ---- GEMM2 (skipped in VAR=2)
        f32x4 acc2[8][2];
#pragma unroll
        for (int m = 0; m < 8; ++m) {
            acc2[m][0] = (f32x4){0.f, 0.f, 0.f, 0.f};
            acc2[m][1] = (f32x4){0.f, 0.f, 0.f, 0.f};
        }
        if constexpr (VAR != 2) {
#pragma unroll
            for (int ks = 0; ks < 12; ++ks) {
                const int j     = ks >> 2;
                const int c0    = (ks & 3) << 5;
                const int shift = (2 - j) * DIL;
#pragma unroll
                for (int m = 0; m < 8; ++m) {
                    f16x8 af = *(const f16x8*)&hs[m * 16 + shift + l15][c0 + kg * 8];
                    acc2[m][0] = __builtin_amdgcn_mfma_f32_16x16x32_f16(af, w2[ks][0], acc2[m][0], 0, 0, 0);
                    acc2[m][1] = __builtin_amdgcn_mfma_f32_16x16x32_f16(af, w2[ks][1], acc2[m][1], 0, 0, 0);
                }
            }
        }

        // ---- epilogue (VAR=3: computed, kept live, not stored)
#pragma unroll
        for (int m = 0; m < 8; ++m) {
#pragma unroll
            for (int nn = 0; nn < 2; ++nn) {
                const float bv = nn ? bv2_1 : bv2_0;
                const int f = nc + nn * 16 + l15;
#pragma unroll
                for (int i = 0; i < 4; ++i) {
                    const int r = m * 16 + kg * 4 + i;
                    const int t = t0 + r;
                    const int nv = 1 + (t < TLEN - DIL) + (t < TLEN - 2 * DIL);
                    float v = acc2[m][nn][i] + (float)nv * bv;
                    v = fmaxf(v, 0.0f);
                    v = fmaxf(v + (float)xs[r][f], 0.0f);
                    if constexpr (VAR == 3) {
                        asm volatile("" :: "v"(v));
                    } else {
                        out[((size_t)b * TLEN + t) * CH + f] = v;
                    }
                }
            }
        }

        if (rep + 1 < REPS) __syncthreads();   // xs reused next rep
    }
}

// ---------------------------------------------------------------------------
extern "C" void kernel_launch(void* const* d_in, const int* in_sizes, int n_in,
                              void* d_out, int out_size, void* d_ws, size_t ws_size,
                              hipStream_t stream) {
    const float* x  = (const float*)d_in[0];
    const float* W1 = (const float*)d_in[1];
    const float* b1 = (const float*)d_in[2];
    const float* W2 = (const float*)d_in[3];
    const float* b2 = (const float*)d_in[4];
    float* out = (float*)d_out;

    _Float16* Wt1 = (_Float16*)d_ws;
    _Float16* Wt2 = Wt1 + KW * CH * CH;

    prep_weights_kernel<<<(2 * KW * CH * CH + 255) / 256, 256, 0, stream>>>(W1, W2, Wt1, Wt2);

    const int grid = BATCH * (TLEN / BM);   // 1024 blocks

    // Ablation probes (garbage/partial output — fully overwritten by VAR=0
    // below, which writes every output element). Durations read via rocprof.
    fused_deconv_kernel<1, 2><<<grid, 256, 0, stream>>>(x, Wt1, b1, Wt2, b2, out);
    fused_deconv_kernel<2, 2><<<grid, 256, 0, stream>>>(x, Wt1, b1, Wt2, b2, out);
    fused_deconv_kernel<3, 2><<<grid, 256, 0, stream>>>(x, Wt1, b1, Wt2, b2, out);

    // The real kernel — last, produces the correct output.
    fused_deconv_kernel<0, 1><<<grid, 256, 0, stream>>>(x, Wt1, b1, Wt2, b2, out);
}